// Round 3
// baseline (1595.503 us; speedup 1.0000x reference)
//
#include <hip/hip_runtime.h>
#include <hip/hip_bf16.h>

// GraphFilter: out = sum_k (S^k x) @ W_k,  S = symmetric scatter-add adjacency
// N=100000, E=3200000, FIN=FOUT=256, K=4.
// Round 3: spmm v2 — 2 neighbors per dwordx4 gather (half-wave each), adj
// stores pre-scaled byte offsets, 8-neighbor unroll (4 gathers in flight).
// CSR build (bucketed radix) and MFMA GEMM unchanged.

#define NNODES 100000
#define NEDGES 3200000
#define FINF   256
#define FOUTF  256
#define KTOT   1024            // K * FIN
#define ROWB   2048            // bytes per z row (KTOT * 2)
#define MPAD   100096          // 782 * 128
#define MTILES 782
#define NB     782             // node buckets: node >> 7
#define FILLB  1024
#define CHUNK  3125            // 1024*3125 = 3.2M edges

typedef __attribute__((ext_vector_type(8))) short bf16x8;
typedef __attribute__((ext_vector_type(4))) float f32x4;

__device__ __forceinline__ float bf2f(unsigned short u) {
  return __uint_as_float(((unsigned int)u) << 16);
}
__device__ __forceinline__ unsigned short f2bf(float f) {
  unsigned int u = __float_as_uint(f);
  unsigned int r = (u + 0x7fffu + ((u >> 16) & 1u)) >> 16;
  return (unsigned short)r;
}

__device__ __forceinline__ void async_ld16(const void* g, void* l) {
  __builtin_amdgcn_global_load_lds(
      (const __attribute__((address_space(1))) unsigned int*)g,
      (__attribute__((address_space(3))) unsigned int*)l, 16, 0, 0);
}

// ---------------- bucketed CSR build ----------------

__global__ __launch_bounds__(256)
void bucket_count_kernel(const int* __restrict__ ei, int* __restrict__ bcount) {
  __shared__ int h[NB];
  for (int i = threadIdx.x; i < NB; i += 256) h[i] = 0;
  __syncthreads();
  for (int e = blockIdx.x * 256 + threadIdx.x; e < NEDGES; e += gridDim.x * 256) {
    int s = ei[e];
    int d = ei[NEDGES + e];
    atomicAdd(&h[d >> 7], 1);
    atomicAdd(&h[s >> 7], 1);
  }
  __syncthreads();
  for (int i = threadIdx.x; i < NB; i += 256) {
    int c = h[i];
    if (c) atomicAdd(&bcount[i], c);
  }
}

__global__ __launch_bounds__(1024)
void bucket_scan_kernel(const int* __restrict__ bcount, int* __restrict__ bbase,
                        int* __restrict__ bcursor) {
  __shared__ int ws[16];
  int t = threadIdx.x, lane = t & 63, wv = t >> 6;
  int v = (t < NB) ? bcount[t] : 0;
  int s = v;
  #pragma unroll
  for (int off = 1; off < 64; off <<= 1) {
    int tmp = __shfl_up(s, off, 64);
    if (lane >= off) s += tmp;
  }
  if (lane == 63) ws[wv] = s;
  __syncthreads();
  if (t == 0) {
    int run = 0;
    #pragma unroll
    for (int k = 0; k < 16; ++k) { int tmp = ws[k]; ws[k] = run; run += tmp; }
  }
  __syncthreads();
  int excl = s + ws[wv] - v;
  if (t < NB) { bbase[t] = excl; bcursor[t] = excl; }
  if (t == NB) bbase[NB] = excl;   // total = 2E
}

__global__ __launch_bounds__(256)
void bin_fill_kernel(const int* __restrict__ ei, int* __restrict__ bcursor,
                     unsigned long long* __restrict__ binned) {
  __shared__ int h[NB];
  for (int i = threadIdx.x; i < NB; i += 256) h[i] = 0;
  __syncthreads();
  const int e0 = blockIdx.x * CHUNK;
  const int e1 = (e0 + CHUNK < NEDGES) ? e0 + CHUNK : NEDGES;
  for (int e = e0 + threadIdx.x; e < e1; e += 256) {
    int s = ei[e];
    int d = ei[NEDGES + e];
    atomicAdd(&h[d >> 7], 1);
    atomicAdd(&h[s >> 7], 1);
  }
  __syncthreads();
  for (int i = threadIdx.x; i < NB; i += 256) {
    int c = h[i];
    h[i] = c ? atomicAdd(&bcursor[i], c) : 0;
  }
  __syncthreads();
  for (int e = e0 + threadIdx.x; e < e1; e += 256) {
    int s = ei[e];
    int d = ei[NEDGES + e];
    int p = atomicAdd(&h[d >> 7], 1);
    binned[p] = ((unsigned long long)d << 32) | (unsigned int)s;
    int q = atomicAdd(&h[s >> 7], 1);
    binned[q] = ((unsigned long long)s << 32) | (unsigned int)d;
  }
}

// adj entries are PRE-SCALED byte offsets (nbr * ROWB) for the spmm gather.
__global__ __launch_bounds__(256)
void bucket_csr_kernel(const unsigned long long* __restrict__ binned,
                       const int* __restrict__ bbase,
                       int* __restrict__ row_ptr, int* __restrict__ adj) {
  __shared__ int cnt[128];
  __shared__ int cur[128];
  const int b = blockIdx.x;
  const int node0 = b << 7;
  const int base = bbase[b];
  const int end = bbase[b + 1];
  const int tid = threadIdx.x;
  if (tid < 128) cnt[tid] = 0;
  __syncthreads();
  for (int i = base + tid; i < end; i += 256) {
    unsigned long long v = binned[i];
    int owner = (int)(v >> 32);
    atomicAdd(&cnt[owner - node0], 1);
  }
  __syncthreads();
  if (tid < 128) {
    int ex = 0;
    #pragma unroll 8
    for (int j = 0; j < 128; ++j) {
      int c = cnt[j];
      ex += (j < tid) ? c : 0;
    }
    int node = node0 + tid;
    if (node < NNODES) row_ptr[node] = base + ex;
    cur[tid] = base + ex;
  }
  if (tid == 0 && b == NB - 1) row_ptr[NNODES] = end;
  __syncthreads();
  for (int i = base + tid; i < end; i += 256) {
    unsigned long long v = binned[i];
    int owner = (int)(v >> 32);
    int nbr = (int)(v & 0xffffffffu);
    int p = atomicAdd(&cur[owner - node0], 1);
    adj[p] = nbr << 11;                       // byte offset = nbr * ROWB
  }
}

// ---------------- conversions ----------------

__global__ void convert_x_kernel(const float* __restrict__ x, unsigned short* __restrict__ z) {
  int idx = blockIdx.x * 256 + threadIdx.x;
  int row = idx >> 8;
  int c4 = (idx & 255) << 2;
  if (row >= MPAD) return;
  if (row < NNODES) {
    if (c4 < FINF) {
      float4 xv = *(const float4*)&x[(size_t)row * FINF + c4];
      ushort4 o;
      o.x = f2bf(xv.x); o.y = f2bf(xv.y); o.z = f2bf(xv.z); o.w = f2bf(xv.w);
      *(ushort4*)&z[(size_t)row * KTOT + c4] = o;
    }
  } else {
    *(ushort4*)&z[(size_t)row * KTOT + c4] = make_ushort4(0, 0, 0, 0);
  }
}

__global__ void convert_w_kernel(const float* __restrict__ w, unsigned short* __restrict__ Bt) {
  int idx = blockIdx.x * 256 + threadIdx.x;
  int o = idx >> 10, kk = idx & 1023;
  Bt[idx] = f2bf(w[(size_t)kk * FOUTF + o]);
}

// ---------------- SpMM v2 (gather, wave/node, 2 rows per dwordx4) ----------------
// lane loads 16B: lanes 0-31 cover neighbor A's 512B row, lanes 32-63 neighbor B.
// adj holds byte offsets. Half-wave partials merged by one shfl_xor(32) at end.

#define ACC4(v)                                        \
  { a[0] += __uint_as_float((v).x << 16);              \
    a[1] += __uint_as_float((v).x & 0xffff0000u);      \
    a[2] += __uint_as_float((v).y << 16);              \
    a[3] += __uint_as_float((v).y & 0xffff0000u);      \
    a[4] += __uint_as_float((v).z << 16);              \
    a[5] += __uint_as_float((v).z & 0xffff0000u);      \
    a[6] += __uint_as_float((v).w << 16);              \
    a[7] += __uint_as_float((v).w & 0xffff0000u); }

__global__ __launch_bounds__(256)
void spmm_kernel(const unsigned short* __restrict__ zin,   // z + (k-1)*256
                 unsigned short* __restrict__ zout,        // z + k*256
                 const int* __restrict__ row_ptr,
                 const int* __restrict__ adjb) {
  const int wid = (blockIdx.x * 256 + threadIdx.x) >> 6;
  const int lane = threadIdx.x & 63;
  if (wid >= NNODES) return;
  const int beg = row_ptr[wid];
  const int end = row_ptr[wid + 1];
  const int half = lane >> 5;
  const int lb = (lane & 31) << 4;          // byte offset within 512B row
  const char* zb = (const char*)zin;
  const int ZPAD = NNODES << 11;            // all-zero pad row offset

  float a[8] = {0.f, 0.f, 0.f, 0.f, 0.f, 0.f, 0.f, 0.f};
  int j = beg;

  // parity peel so int2 adj loads are 8B-aligned
  if ((j & 1) && j < end) {
    int off = half ? ZPAD : adjb[j];
    uint4 v = *(const uint4*)(zb + off + lb);
    ACC4(v);
    ++j;
  }
  for (; j + 8 <= end; j += 8) {
    int2 o0 = *(const int2*)&adjb[j];
    int2 o1 = *(const int2*)&adjb[j + 2];
    int2 o2 = *(const int2*)&adjb[j + 4];
    int2 o3 = *(const int2*)&adjb[j + 6];
    uint4 v0 = *(const uint4*)(zb + (half ? o0.y : o0.x) + lb);
    uint4 v1 = *(const uint4*)(zb + (half ? o1.y : o1.x) + lb);
    uint4 v2 = *(const uint4*)(zb + (half ? o2.y : o2.x) + lb);
    uint4 v3 = *(const uint4*)(zb + (half ? o3.y : o3.x) + lb);
    ACC4(v0); ACC4(v1); ACC4(v2); ACC4(v3);
  }
  for (; j + 2 <= end; j += 2) {
    int2 o = *(const int2*)&adjb[j];
    uint4 v = *(const uint4*)(zb + (half ? o.y : o.x) + lb);
    ACC4(v);
  }
  if (j < end) {
    int off = half ? ZPAD : adjb[j];
    uint4 v = *(const uint4*)(zb + off + lb);
    ACC4(v);
  }

  #pragma unroll
  for (int i = 0; i < 8; ++i) a[i] += __shfl_xor(a[i], 32, 64);

  if (half == 0) {
    uint4 o;
    o.x = (unsigned int)f2bf(a[0]) | ((unsigned int)f2bf(a[1]) << 16);
    o.y = (unsigned int)f2bf(a[2]) | ((unsigned int)f2bf(a[3]) << 16);
    o.z = (unsigned int)f2bf(a[4]) | ((unsigned int)f2bf(a[5]) << 16);
    o.w = (unsigned int)f2bf(a[6]) | ((unsigned int)f2bf(a[7]) << 16);
    *(uint4*)((char*)zout + ((size_t)wid << 11) + lb) = o;
  }
}

// ---------------- GEMM: [MPAD,1024]bf16 @ [1024,256]bf16 -> fp32 ----------------

__global__ __launch_bounds__(256)
void gemm_kernel(const unsigned short* __restrict__ A,   // [MPAD][1024]
                 const unsigned short* __restrict__ Bt,  // [256][1024]
                 float* __restrict__ C) {                 // [NNODES][256]
  __shared__ __align__(16) unsigned short As[128 * 32];
  __shared__ __align__(16) unsigned short Bs[128 * 32];
  const int tid = threadIdx.x;
  const int lane = tid & 63;
  const int wave = tid >> 6;
  const int bm = blockIdx.x >> 1;
  const int bn = blockIdx.x & 1;
  const int wr = wave >> 1, wc = wave & 1;

  const int rowA_base = bm * 128;
  const int colB_base = bn * 128;
  const int sub_r = lane >> 2;
  const int kp = (lane & 3) << 3;

  f32x4 acc[4][4] = {};

  for (int k0 = 0; k0 < KTOT; k0 += 32) {
    __syncthreads();
    #pragma unroll
    for (int i = 0; i < 2; ++i) {
      int chunk = i * 4 + wave;
      int row = chunk * 16 + sub_r;
      const unsigned short* ga = A + (size_t)(rowA_base + row) * KTOT + k0 + kp;
      async_ld16(ga, &As[chunk * 512]);
      const unsigned short* gb = Bt + (size_t)(colB_base + row) * KTOT + k0 + kp;
      async_ld16(gb, &Bs[chunk * 512]);
    }
    __syncthreads();

    bf16x8 a[4], b[4];
    #pragma unroll
    for (int m = 0; m < 4; ++m)
      a[m] = *(const bf16x8*)&As[(wr * 64 + m * 16 + (lane & 15)) * 32 + (lane >> 4) * 8];
    #pragma unroll
    for (int n = 0; n < 4; ++n)
      b[n] = *(const bf16x8*)&Bs[(wc * 64 + n * 16 + (lane & 15)) * 32 + (lane >> 4) * 8];
    #pragma unroll
    for (int m = 0; m < 4; ++m) {
      #pragma unroll
      for (int n = 0; n < 4; ++n)
        acc[m][n] = __builtin_amdgcn_mfma_f32_16x16x32_bf16(a[m], b[n], acc[m][n], 0, 0, 0);
    }
  }

  const int ccol0 = colB_base + wc * 64 + (lane & 15);
  const int crow0 = rowA_base + wr * 64 + ((lane >> 4) << 2);
  #pragma unroll
  for (int m = 0; m < 4; ++m) {
    #pragma unroll
    for (int j = 0; j < 4; ++j) {
      int r = crow0 + m * 16 + j;
      if (r < NNODES) {
        float* cp = C + (size_t)r * FOUTF + ccol0;
        #pragma unroll
        for (int n = 0; n < 4; ++n) cp[n * 16] = acc[m][n][j];
      }
    }
  }
}

// ---------------- launch ----------------

extern "C" void kernel_launch(void* const* d_in, const int* in_sizes, int n_in,
                              void* d_out, int out_size, void* d_ws, size_t ws_size,
                              hipStream_t stream) {
  (void)in_sizes; (void)n_in; (void)out_size; (void)ws_size;
  const float* x  = (const float*)d_in[0];
  const int*   ei = (const int*)d_in[1];
  const float* w  = (const float*)d_in[2];
  float* out = (float*)d_out;

  char* ws = (char*)d_ws;
  size_t off = 0;
  auto carve = [&](size_t bytes) -> void* {
    void* p = ws + off;
    off = (off + bytes + 255) & ~(size_t)255;
    return p;
  };
  unsigned short* z  = (unsigned short*)carve((size_t)MPAD * KTOT * 2);  // 205 MB
  unsigned short* Bt = (unsigned short*)carve((size_t)FOUTF * KTOT * 2);
  int* row_ptr       = (int*)carve((size_t)(NNODES + 1) * 4);
  int* adj           = (int*)carve((size_t)2 * NEDGES * 4);
  int* bcount        = (int*)carve((size_t)(NB + 1) * 4);
  int* bbase         = (int*)carve((size_t)(NB + 1) * 4);
  int* bcursor       = (int*)carve((size_t)(NB + 1) * 4);
  // binned (51.2 MB) aliases head of z: fully rewritten by convert_x/spmm
  // before gemm reads it (stream-ordered).
  unsigned long long* binned = (unsigned long long*)z;

  hipMemsetAsync(bcount, 0, (size_t)(NB + 1) * 4, stream);

  bucket_count_kernel<<<1024, 256, 0, stream>>>(ei, bcount);
  bucket_scan_kernel<<<1, 1024, 0, stream>>>(bcount, bbase, bcursor);
  bin_fill_kernel<<<FILLB, 256, 0, stream>>>(ei, bcursor, binned);
  bucket_csr_kernel<<<NB, 256, 0, stream>>>(binned, bbase, row_ptr, adj);

  convert_x_kernel<<<MPAD, 256, 0, stream>>>(x, z);
  convert_w_kernel<<<1024, 256, 0, stream>>>(w, Bt);

  for (int k = 1; k < 4; ++k) {
    spmm_kernel<<<(NNODES + 3) / 4, 256, 0, stream>>>(
        z + (size_t)(k - 1) * FINF, z + (size_t)k * FINF, row_ptr, adj);
  }

  gemm_kernel<<<MTILES * 2, 256, 0, stream>>>(z, Bt, out);
}

// Round 4
// 1523.963 us; speedup vs baseline: 1.0469x; 1.0469x over previous
//
#include <hip/hip_runtime.h>
#include <hip/hip_bf16.h>

// GraphFilter: out = sum_k (S^k x) @ W_k,  S = symmetric scatter-add adjacency
// N=100000, E=3200000, FIN=FOUT=256, K=4.
// Round 4: feature-sliced SpMM — each hop split into 2 passes of 128 features
// (256B/row gather) to shrink the gathered working set 51.2MB -> 25.6MB/pass
// and raise per-XCD L2 hit rate (spmm is L2-miss-path bound at ~3.8 TB/s).
// Full-wave row gather (4B/lane), prescaled byte offsets, 8-deep unroll.

#define NNODES 100000
#define NEDGES 3200000
#define FINF   256
#define FOUTF  256
#define KTOT   1024            // K * FIN
#define ROWB   2048            // bytes per z row
#define MPAD   100096          // 782 * 128
#define MTILES 782
#define NB     782             // node buckets: node >> 7
#define FILLB  1024
#define CHUNK  3125            // 1024*3125 = 3.2M edges

typedef __attribute__((ext_vector_type(8))) short bf16x8;
typedef __attribute__((ext_vector_type(4))) float f32x4;

__device__ __forceinline__ float bf2f(unsigned short u) {
  return __uint_as_float(((unsigned int)u) << 16);
}
__device__ __forceinline__ unsigned short f2bf(float f) {
  unsigned int u = __float_as_uint(f);
  unsigned int r = (u + 0x7fffu + ((u >> 16) & 1u)) >> 16;
  return (unsigned short)r;
}

__device__ __forceinline__ void async_ld16(const void* g, void* l) {
  __builtin_amdgcn_global_load_lds(
      (const __attribute__((address_space(1))) unsigned int*)g,
      (__attribute__((address_space(3))) unsigned int*)l, 16, 0, 0);
}

// ---------------- bucketed CSR build ----------------

__global__ __launch_bounds__(256)
void bucket_count_kernel(const int* __restrict__ ei, int* __restrict__ bcount) {
  __shared__ int h[NB];
  for (int i = threadIdx.x; i < NB; i += 256) h[i] = 0;
  __syncthreads();
  for (int e = blockIdx.x * 256 + threadIdx.x; e < NEDGES; e += gridDim.x * 256) {
    int s = ei[e];
    int d = ei[NEDGES + e];
    atomicAdd(&h[d >> 7], 1);
    atomicAdd(&h[s >> 7], 1);
  }
  __syncthreads();
  for (int i = threadIdx.x; i < NB; i += 256) {
    int c = h[i];
    if (c) atomicAdd(&bcount[i], c);
  }
}

__global__ __launch_bounds__(1024)
void bucket_scan_kernel(const int* __restrict__ bcount, int* __restrict__ bbase,
                        int* __restrict__ bcursor) {
  __shared__ int ws[16];
  int t = threadIdx.x, lane = t & 63, wv = t >> 6;
  int v = (t < NB) ? bcount[t] : 0;
  int s = v;
  #pragma unroll
  for (int off = 1; off < 64; off <<= 1) {
    int tmp = __shfl_up(s, off, 64);
    if (lane >= off) s += tmp;
  }
  if (lane == 63) ws[wv] = s;
  __syncthreads();
  if (t == 0) {
    int run = 0;
    #pragma unroll
    for (int k = 0; k < 16; ++k) { int tmp = ws[k]; ws[k] = run; run += tmp; }
  }
  __syncthreads();
  int excl = s + ws[wv] - v;
  if (t < NB) { bbase[t] = excl; bcursor[t] = excl; }
  if (t == NB) bbase[NB] = excl;   // total = 2E
}

__global__ __launch_bounds__(256)
void bin_fill_kernel(const int* __restrict__ ei, int* __restrict__ bcursor,
                     unsigned long long* __restrict__ binned) {
  __shared__ int h[NB];
  for (int i = threadIdx.x; i < NB; i += 256) h[i] = 0;
  __syncthreads();
  const int e0 = blockIdx.x * CHUNK;
  const int e1 = (e0 + CHUNK < NEDGES) ? e0 + CHUNK : NEDGES;
  for (int e = e0 + threadIdx.x; e < e1; e += 256) {
    int s = ei[e];
    int d = ei[NEDGES + e];
    atomicAdd(&h[d >> 7], 1);
    atomicAdd(&h[s >> 7], 1);
  }
  __syncthreads();
  for (int i = threadIdx.x; i < NB; i += 256) {
    int c = h[i];
    h[i] = c ? atomicAdd(&bcursor[i], c) : 0;
  }
  __syncthreads();
  for (int e = e0 + threadIdx.x; e < e1; e += 256) {
    int s = ei[e];
    int d = ei[NEDGES + e];
    int p = atomicAdd(&h[d >> 7], 1);
    binned[p] = ((unsigned long long)d << 32) | (unsigned int)s;
    int q = atomicAdd(&h[s >> 7], 1);
    binned[q] = ((unsigned long long)s << 32) | (unsigned int)d;
  }
}

// adj entries are PRE-SCALED row byte offsets (nbr * ROWB).
__global__ __launch_bounds__(256)
void bucket_csr_kernel(const unsigned long long* __restrict__ binned,
                       const int* __restrict__ bbase,
                       int* __restrict__ row_ptr, int* __restrict__ adj) {
  __shared__ int cnt[128];
  __shared__ int cur[128];
  const int b = blockIdx.x;
  const int node0 = b << 7;
  const int base = bbase[b];
  const int end = bbase[b + 1];
  const int tid = threadIdx.x;
  if (tid < 128) cnt[tid] = 0;
  __syncthreads();
  for (int i = base + tid; i < end; i += 256) {
    unsigned long long v = binned[i];
    int owner = (int)(v >> 32);
    atomicAdd(&cnt[owner - node0], 1);
  }
  __syncthreads();
  if (tid < 128) {
    int ex = 0;
    #pragma unroll 8
    for (int j = 0; j < 128; ++j) {
      int c = cnt[j];
      ex += (j < tid) ? c : 0;
    }
    int node = node0 + tid;
    if (node < NNODES) row_ptr[node] = base + ex;
    cur[tid] = base + ex;
  }
  if (tid == 0 && b == NB - 1) row_ptr[NNODES] = end;
  __syncthreads();
  for (int i = base + tid; i < end; i += 256) {
    unsigned long long v = binned[i];
    int owner = (int)(v >> 32);
    int nbr = (int)(v & 0xffffffffu);
    int p = atomicAdd(&cur[owner - node0], 1);
    adj[p] = nbr << 11;                       // byte offset = nbr * ROWB
  }
}

// ---------------- conversions ----------------

__global__ void convert_x_kernel(const float* __restrict__ x, unsigned short* __restrict__ z) {
  int idx = blockIdx.x * 256 + threadIdx.x;
  int row = idx >> 8;
  int c4 = (idx & 255) << 2;
  if (row >= MPAD) return;
  if (row < NNODES) {
    if (c4 < FINF) {
      float4 xv = *(const float4*)&x[(size_t)row * FINF + c4];
      ushort4 o;
      o.x = f2bf(xv.x); o.y = f2bf(xv.y); o.z = f2bf(xv.z); o.w = f2bf(xv.w);
      *(ushort4*)&z[(size_t)row * KTOT + c4] = o;
    }
  } else {
    *(ushort4*)&z[(size_t)row * KTOT + c4] = make_ushort4(0, 0, 0, 0);
  }
}

__global__ void convert_w_kernel(const float* __restrict__ w, unsigned short* __restrict__ Bt) {
  int idx = blockIdx.x * 256 + threadIdx.x;
  int o = idx >> 10, kk = idx & 1023;
  Bt[idx] = f2bf(w[(size_t)kk * FOUTF + o]);
}

// ---------------- SpMM v3: feature-sliced gather (128 feats = 256B / pass) ----
// Full wave per neighbor row; lane reads 4B (2 bf16) at zin_slice + off + lane*4.
// adj holds wave-uniform prescaled byte offsets -> scalar loads; 8-deep unroll.

#define ACC1(v) { a0 += __uint_as_float((v) << 16); \
                  a1 += __uint_as_float((v) & 0xffff0000u); }

__global__ __launch_bounds__(256)
void spmm_kernel(const unsigned short* __restrict__ zin,   // slice base (hop-1)
                 unsigned short* __restrict__ zout,        // slice base (hop)
                 const int* __restrict__ row_ptr,
                 const int* __restrict__ adjb) {
  const int wid = (blockIdx.x * 256 + threadIdx.x) >> 6;
  const int lane = threadIdx.x & 63;
  if (wid >= NNODES) return;
  const int beg = row_ptr[wid];
  const int end = row_ptr[wid + 1];
  const int lb = lane << 2;                 // 4B/lane, 256B per row slice
  const char* zb = (const char*)zin;

  float a0 = 0.f, a1 = 0.f;
  int j = beg;
  for (; j + 8 <= end; j += 8) {
    int o0 = adjb[j + 0], o1 = adjb[j + 1], o2 = adjb[j + 2], o3 = adjb[j + 3];
    int o4 = adjb[j + 4], o5 = adjb[j + 5], o6 = adjb[j + 6], o7 = adjb[j + 7];
    unsigned int v0 = *(const unsigned int*)(zb + o0 + lb);
    unsigned int v1 = *(const unsigned int*)(zb + o1 + lb);
    unsigned int v2 = *(const unsigned int*)(zb + o2 + lb);
    unsigned int v3 = *(const unsigned int*)(zb + o3 + lb);
    unsigned int v4 = *(const unsigned int*)(zb + o4 + lb);
    unsigned int v5 = *(const unsigned int*)(zb + o5 + lb);
    unsigned int v6 = *(const unsigned int*)(zb + o6 + lb);
    unsigned int v7 = *(const unsigned int*)(zb + o7 + lb);
    ACC1(v0); ACC1(v1); ACC1(v2); ACC1(v3);
    ACC1(v4); ACC1(v5); ACC1(v6); ACC1(v7);
  }
  for (; j < end; ++j) {
    unsigned int v = *(const unsigned int*)(zb + adjb[j] + lb);
    ACC1(v);
  }

  unsigned int o = (unsigned int)f2bf(a0) | ((unsigned int)f2bf(a1) << 16);
  *(unsigned int*)((char*)zout + ((size_t)wid << 11) + lb) = o;
}

// ---------------- GEMM: [MPAD,1024]bf16 @ [1024,256]bf16 -> fp32 ----------------

__global__ __launch_bounds__(256)
void gemm_kernel(const unsigned short* __restrict__ A,   // [MPAD][1024]
                 const unsigned short* __restrict__ Bt,  // [256][1024]
                 float* __restrict__ C) {                 // [NNODES][256]
  __shared__ __align__(16) unsigned short As[128 * 32];
  __shared__ __align__(16) unsigned short Bs[128 * 32];
  const int tid = threadIdx.x;
  const int lane = tid & 63;
  const int wave = tid >> 6;
  const int bm = blockIdx.x >> 1;
  const int bn = blockIdx.x & 1;
  const int wr = wave >> 1, wc = wave & 1;

  const int rowA_base = bm * 128;
  const int colB_base = bn * 128;
  const int sub_r = lane >> 2;
  const int kp = (lane & 3) << 3;

  f32x4 acc[4][4] = {};

  for (int k0 = 0; k0 < KTOT; k0 += 32) {
    __syncthreads();
    #pragma unroll
    for (int i = 0; i < 2; ++i) {
      int chunk = i * 4 + wave;
      int row = chunk * 16 + sub_r;
      const unsigned short* ga = A + (size_t)(rowA_base + row) * KTOT + k0 + kp;
      async_ld16(ga, &As[chunk * 512]);
      const unsigned short* gb = Bt + (size_t)(colB_base + row) * KTOT + k0 + kp;
      async_ld16(gb, &Bs[chunk * 512]);
    }
    __syncthreads();

    bf16x8 a[4], b[4];
    #pragma unroll
    for (int m = 0; m < 4; ++m)
      a[m] = *(const bf16x8*)&As[(wr * 64 + m * 16 + (lane & 15)) * 32 + (lane >> 4) * 8];
    #pragma unroll
    for (int n = 0; n < 4; ++n)
      b[n] = *(const bf16x8*)&Bs[(wc * 64 + n * 16 + (lane & 15)) * 32 + (lane >> 4) * 8];
    #pragma unroll
    for (int m = 0; m < 4; ++m) {
      #pragma unroll
      for (int n = 0; n < 4; ++n)
        acc[m][n] = __builtin_amdgcn_mfma_f32_16x16x32_bf16(a[m], b[n], acc[m][n], 0, 0, 0);
    }
  }

  const int ccol0 = colB_base + wc * 64 + (lane & 15);
  const int crow0 = rowA_base + wr * 64 + ((lane >> 4) << 2);
  #pragma unroll
  for (int m = 0; m < 4; ++m) {
    #pragma unroll
    for (int j = 0; j < 4; ++j) {
      int r = crow0 + m * 16 + j;
      if (r < NNODES) {
        float* cp = C + (size_t)r * FOUTF + ccol0;
        #pragma unroll
        for (int n = 0; n < 4; ++n) cp[n * 16] = acc[m][n][j];
      }
    }
  }
}

// ---------------- launch ----------------

extern "C" void kernel_launch(void* const* d_in, const int* in_sizes, int n_in,
                              void* d_out, int out_size, void* d_ws, size_t ws_size,
                              hipStream_t stream) {
  (void)in_sizes; (void)n_in; (void)out_size; (void)ws_size;
  const float* x  = (const float*)d_in[0];
  const int*   ei = (const int*)d_in[1];
  const float* w  = (const float*)d_in[2];
  float* out = (float*)d_out;

  char* ws = (char*)d_ws;
  size_t off = 0;
  auto carve = [&](size_t bytes) -> void* {
    void* p = ws + off;
    off = (off + bytes + 255) & ~(size_t)255;
    return p;
  };
  unsigned short* z  = (unsigned short*)carve((size_t)MPAD * KTOT * 2);  // 205 MB
  unsigned short* Bt = (unsigned short*)carve((size_t)FOUTF * KTOT * 2);
  int* row_ptr       = (int*)carve((size_t)(NNODES + 1) * 4);
  int* adj           = (int*)carve((size_t)2 * NEDGES * 4);
  int* bcount        = (int*)carve((size_t)(NB + 1) * 4);
  int* bbase         = (int*)carve((size_t)(NB + 1) * 4);
  int* bcursor       = (int*)carve((size_t)(NB + 1) * 4);
  // binned (51.2 MB) aliases head of z: fully consumed by bucket_csr before
  // convert_x/spmm rewrite the region (stream-ordered).
  unsigned long long* binned = (unsigned long long*)z;

  hipMemsetAsync(bcount, 0, (size_t)(NB + 1) * 4, stream);

  bucket_count_kernel<<<1024, 256, 0, stream>>>(ei, bcount);
  bucket_scan_kernel<<<1, 1024, 0, stream>>>(bcount, bbase, bcursor);
  bin_fill_kernel<<<FILLB, 256, 0, stream>>>(ei, bcursor, binned);
  bucket_csr_kernel<<<NB, 256, 0, stream>>>(binned, bbase, row_ptr, adj);

  convert_x_kernel<<<MPAD, 256, 0, stream>>>(x, z);
  convert_w_kernel<<<1024, 256, 0, stream>>>(w, Bt);

  // 3 hops x 2 feature-slice passes (cols [0,128) and [128,256) of each slot)
  for (int k = 1; k < 4; ++k) {
    for (int half = 0; half < 2; ++half) {
      spmm_kernel<<<(NNODES + 3) / 4, 256, 0, stream>>>(
          z + (size_t)(k - 1) * FINF + half * 128,
          z + (size_t)k * FINF + half * 128,
          row_ptr, adj);
    }
  }

  gemm_kernel<<<MTILES * 2, 256, 0, stream>>>(z, Bt, out);
}

// Round 6
// 1031.525 us; speedup vs baseline: 1.5467x; 1.4774x over previous
//
#include <hip/hip_runtime.h>
#include <hip/hip_bf16.h>

// GraphFilter: out = sum_k (S^k x) @ W_k,  S = symmetric scatter-add adjacency
// N=100000, E=3200000, FIN=FOUT=256, K=4.
// Round 6: int8 gather path with PER-ROW scales (s = rowmax/127). spmm is
// beyond-L2-path bound (~3.6 TB/s at any shape), so halve miss bytes like the
// fp8 attempt (r5, failed absmax 94) but with ~6x better accuracy: int8+scale
// RMS err ~0.45% of rowmax vs e4m3's 3.6%. Whole 256-feat row per pass ->
// 3 gather passes total (vs 6 bf16 half-passes). z stays true-scale bf16 for
// the MFMA GEMM. CSR build (bucketed radix) and GEMM unchanged.

#define NNODES 100000
#define NEDGES 3200000
#define FINF   256
#define FOUTF  256
#define KTOT   1024            // K * FIN
#define MPAD   100096          // 782 * 128
#define MTILES 782
#define NB     782             // node buckets: node >> 7
#define FILLB  1024
#define CHUNK  3125            // 1024*3125 = 3.2M edges

typedef __attribute__((ext_vector_type(8))) short bf16x8;
typedef __attribute__((ext_vector_type(4))) float f32x4;

__device__ __forceinline__ unsigned short f2bf(float f) {
  unsigned int u = __float_as_uint(f);
  unsigned int r = (u + 0x7fffu + ((u >> 16) & 1u)) >> 16;
  return (unsigned short)r;
}

__device__ __forceinline__ void async_ld16(const void* g, void* l) {
  __builtin_amdgcn_global_load_lds(
      (const __attribute__((address_space(1))) unsigned int*)g,
      (__attribute__((address_space(3))) unsigned int*)l, 16, 0, 0);
}

// ---------------- bucketed CSR build ----------------

__global__ __launch_bounds__(256)
void bucket_count_kernel(const int* __restrict__ ei, int* __restrict__ bcount) {
  __shared__ int h[NB];
  for (int i = threadIdx.x; i < NB; i += 256) h[i] = 0;
  __syncthreads();
  for (int e = blockIdx.x * 256 + threadIdx.x; e < NEDGES; e += gridDim.x * 256) {
    int s = ei[e];
    int d = ei[NEDGES + e];
    atomicAdd(&h[d >> 7], 1);
    atomicAdd(&h[s >> 7], 1);
  }
  __syncthreads();
  for (int i = threadIdx.x; i < NB; i += 256) {
    int c = h[i];
    if (c) atomicAdd(&bcount[i], c);
  }
}

__global__ __launch_bounds__(1024)
void bucket_scan_kernel(const int* __restrict__ bcount, int* __restrict__ bbase,
                        int* __restrict__ bcursor) {
  __shared__ int ws[16];
  int t = threadIdx.x, lane = t & 63, wv = t >> 6;
  int v = (t < NB) ? bcount[t] : 0;
  int s = v;
  #pragma unroll
  for (int off = 1; off < 64; off <<= 1) {
    int tmp = __shfl_up(s, off, 64);
    if (lane >= off) s += tmp;
  }
  if (lane == 63) ws[wv] = s;
  __syncthreads();
  if (t == 0) {
    int run = 0;
    #pragma unroll
    for (int k = 0; k < 16; ++k) { int tmp = ws[k]; ws[k] = run; run += tmp; }
  }
  __syncthreads();
  int excl = s + ws[wv] - v;
  if (t < NB) { bbase[t] = excl; bcursor[t] = excl; }
  if (t == NB) bbase[NB] = excl;   // total = 2E
}

__global__ __launch_bounds__(256)
void bin_fill_kernel(const int* __restrict__ ei, int* __restrict__ bcursor,
                     unsigned long long* __restrict__ binned) {
  __shared__ int h[NB];
  for (int i = threadIdx.x; i < NB; i += 256) h[i] = 0;
  __syncthreads();
  const int e0 = blockIdx.x * CHUNK;
  const int e1 = (e0 + CHUNK < NEDGES) ? e0 + CHUNK : NEDGES;
  for (int e = e0 + threadIdx.x; e < e1; e += 256) {
    int s = ei[e];
    int d = ei[NEDGES + e];
    atomicAdd(&h[d >> 7], 1);
    atomicAdd(&h[s >> 7], 1);
  }
  __syncthreads();
  for (int i = threadIdx.x; i < NB; i += 256) {
    int c = h[i];
    h[i] = c ? atomicAdd(&bcursor[i], c) : 0;
  }
  __syncthreads();
  for (int e = e0 + threadIdx.x; e < e1; e += 256) {
    int s = ei[e];
    int d = ei[NEDGES + e];
    int p = atomicAdd(&h[d >> 7], 1);
    binned[p] = ((unsigned long long)d << 32) | (unsigned int)s;
    int q = atomicAdd(&h[s >> 7], 1);
    binned[q] = ((unsigned long long)s << 32) | (unsigned int)d;
  }
}

// adj entries are PRE-SCALED q-row byte offsets (nbr * 256); scale byte
// offset for a row is adj>>6 (= nbr*4).
__global__ __launch_bounds__(256)
void bucket_csr_kernel(const unsigned long long* __restrict__ binned,
                       const int* __restrict__ bbase,
                       int* __restrict__ row_ptr, int* __restrict__ adj) {
  __shared__ int cnt[128];
  __shared__ int cur[128];
  const int b = blockIdx.x;
  const int node0 = b << 7;
  const int base = bbase[b];
  const int end = bbase[b + 1];
  const int tid = threadIdx.x;
  if (tid < 128) cnt[tid] = 0;
  __syncthreads();
  for (int i = base + tid; i < end; i += 256) {
    unsigned long long v = binned[i];
    int owner = (int)(v >> 32);
    atomicAdd(&cnt[owner - node0], 1);
  }
  __syncthreads();
  if (tid < 128) {
    int ex = 0;
    #pragma unroll 8
    for (int j = 0; j < 128; ++j) {
      int c = cnt[j];
      ex += (j < tid) ? c : 0;
    }
    int node = node0 + tid;
    if (node < NNODES) row_ptr[node] = base + ex;
    cur[tid] = base + ex;
  }
  if (tid == 0 && b == NB - 1) row_ptr[NNODES] = end;
  __syncthreads();
  for (int i = base + tid; i < end; i += 256) {
    unsigned long long v = binned[i];
    int owner = (int)(v >> 32);
    int nbr = (int)(v & 0xffffffffu);
    int p = atomicAdd(&cur[owner - node0], 1);
    adj[p] = nbr << 8;                        // byte offset into int8 g array
  }
}

// ---------------- conversions ----------------

// Wave per row: z slot0 = bf16(x); g0 = int8 quant of x (biased-unsigned,
// per-row scale s = rowmax/127 in sc0).
__global__ __launch_bounds__(256)
void convert_x_kernel(const float* __restrict__ x,
                      unsigned short* __restrict__ z,
                      unsigned char* __restrict__ g0,
                      float* __restrict__ sc0) {
  const int row = (blockIdx.x * 256 + threadIdx.x) >> 6;
  const int lane = threadIdx.x & 63;
  if (row >= NNODES) return;
  float4 xv = *(const float4*)&x[(size_t)row * FINF + (lane << 2)];

  ushort4 o;
  o.x = f2bf(xv.x); o.y = f2bf(xv.y); o.z = f2bf(xv.z); o.w = f2bf(xv.w);
  *(ushort4*)&z[(size_t)row * KTOT + (lane << 2)] = o;

  float m = fmaxf(fmaxf(fabsf(xv.x), fabsf(xv.y)), fmaxf(fabsf(xv.z), fabsf(xv.w)));
  #pragma unroll
  for (int i = 1; i < 64; i <<= 1) m = fmaxf(m, __shfl_xor(m, i, 64));
  float inv = (m > 0.f) ? 127.f / m : 0.f;
  unsigned int q0 = (unsigned int)__builtin_rintf(__builtin_fmaf(xv.x, inv, 128.f));
  unsigned int q1 = (unsigned int)__builtin_rintf(__builtin_fmaf(xv.y, inv, 128.f));
  unsigned int q2 = (unsigned int)__builtin_rintf(__builtin_fmaf(xv.z, inv, 128.f));
  unsigned int q3 = (unsigned int)__builtin_rintf(__builtin_fmaf(xv.w, inv, 128.f));
  *(unsigned int*)(g0 + (size_t)row * 256 + (lane << 2)) =
      q0 | (q1 << 8) | (q2 << 16) | (q3 << 24);
  if (lane == 0) sc0[row] = m * (1.f / 127.f);
}

// zero pad rows [NNODES, MPAD): all 1024 cols (one block per row).
__global__ void zero_pad_kernel(unsigned short* __restrict__ z) {
  size_t row = NNODES + blockIdx.x;
  *(ushort4*)&z[row * KTOT + (threadIdx.x << 2)] = make_ushort4(0, 0, 0, 0);
}

// Bt[o][kk] = w[kk*256 + o]  (bf16, transposed)
__global__ void convert_w_kernel(const float* __restrict__ w, unsigned short* __restrict__ Bt) {
  int idx = blockIdx.x * 256 + threadIdx.x;
  int o = idx >> 10, kk = idx & 1023;
  Bt[idx] = f2bf(w[(size_t)kk * FOUTF + o]);
}

// ---------------- SpMM int8 (gather, wave/node, whole 256-feat row/pass) ----
// lane reads 4B = 4 int8 feats; acc += s*(u_byte); bias 128*sum(s) subtracted
// at the end. Epilogue: bf16 z slot + re-quantized int8 row (+scale).

#define DECQ(vv, ss)                                        \
  { acc0 += (ss) * (float)((vv) & 255u);                    \
    acc1 += (ss) * (float)(((vv) >> 8) & 255u);             \
    acc2 += (ss) * (float)(((vv) >> 16) & 255u);            \
    acc3 += (ss) * (float)((vv) >> 24);                     \
    ssum += (ss); }

__global__ __launch_bounds__(256)
void spmm_q8_kernel(const unsigned char* __restrict__ gin,   // [N][256] int8
                    const float* __restrict__ sin,           // [N] scales
                    unsigned char* __restrict__ gout,        // [N][256] or null
                    float* __restrict__ sout,                // [N] or null
                    unsigned short* __restrict__ zslot,      // z + k*256
                    const int* __restrict__ row_ptr,
                    const int* __restrict__ adjb) {
  const int wid = (blockIdx.x * 256 + threadIdx.x) >> 6;
  const int lane = threadIdx.x & 63;
  if (wid >= NNODES) return;
  const int beg = row_ptr[wid];
  const int end = row_ptr[wid + 1];
  const int lb = lane << 2;
  const char* scb = (const char*)sin;

  float acc0 = 0.f, acc1 = 0.f, acc2 = 0.f, acc3 = 0.f, ssum = 0.f;
  int j = beg;
  for (; j + 4 <= end; j += 4) {
    int o0 = adjb[j + 0], o1 = adjb[j + 1], o2 = adjb[j + 2], o3 = adjb[j + 3];
    float s0 = *(const float*)(scb + (o0 >> 6));
    float s1 = *(const float*)(scb + (o1 >> 6));
    float s2 = *(const float*)(scb + (o2 >> 6));
    float s3 = *(const float*)(scb + (o3 >> 6));
    unsigned int v0 = *(const unsigned int*)(gin + o0 + lb);
    unsigned int v1 = *(const unsigned int*)(gin + o1 + lb);
    unsigned int v2 = *(const unsigned int*)(gin + o2 + lb);
    unsigned int v3 = *(const unsigned int*)(gin + o3 + lb);
    DECQ(v0, s0); DECQ(v1, s1); DECQ(v2, s2); DECQ(v3, s3);
  }
  for (; j < end; ++j) {
    int o = adjb[j];
    float s = *(const float*)(scb + (o >> 6));
    unsigned int v = *(const unsigned int*)(gin + o + lb);
    DECQ(v, s);
  }

  const float bias = 128.f * ssum;
  const float a0 = acc0 - bias;
  const float a1 = acc1 - bias;
  const float a2 = acc2 - bias;
  const float a3 = acc3 - bias;

  uint2 ob;
  ob.x = (unsigned int)f2bf(a0) | ((unsigned int)f2bf(a1) << 16);
  ob.y = (unsigned int)f2bf(a2) | ((unsigned int)f2bf(a3) << 16);
  *(uint2*)((char*)zslot + ((size_t)wid << 11) + (lane << 3)) = ob;

  if (gout) {
    float m = fmaxf(fmaxf(fabsf(a0), fabsf(a1)), fmaxf(fabsf(a2), fabsf(a3)));
    #pragma unroll
    for (int i = 1; i < 64; i <<= 1) m = fmaxf(m, __shfl_xor(m, i, 64));
    float inv = (m > 0.f) ? 127.f / m : 0.f;
    unsigned int q0 = (unsigned int)__builtin_rintf(__builtin_fmaf(a0, inv, 128.f));
    unsigned int q1 = (unsigned int)__builtin_rintf(__builtin_fmaf(a1, inv, 128.f));
    unsigned int q2 = (unsigned int)__builtin_rintf(__builtin_fmaf(a2, inv, 128.f));
    unsigned int q3 = (unsigned int)__builtin_rintf(__builtin_fmaf(a3, inv, 128.f));
    *(unsigned int*)(gout + (size_t)wid * 256 + lb) =
        q0 | (q1 << 8) | (q2 << 16) | (q3 << 24);
    if (lane == 0) sout[wid] = m * (1.f / 127.f);
  }
}

// ---------------- GEMM: [MPAD,1024]bf16 @ [1024,256]bf16 -> fp32 ----------------

__global__ __launch_bounds__(256)
void gemm_kernel(const unsigned short* __restrict__ A,   // [MPAD][1024]
                 const unsigned short* __restrict__ Bt,  // [256][1024]
                 float* __restrict__ C) {                 // [NNODES][256]
  __shared__ __align__(16) unsigned short As[128 * 32];
  __shared__ __align__(16) unsigned short Bs[128 * 32];
  const int tid = threadIdx.x;
  const int lane = tid & 63;
  const int wave = tid >> 6;
  const int bm = blockIdx.x >> 1;
  const int bn = blockIdx.x & 1;
  const int wr = wave >> 1, wc = wave & 1;

  const int rowA_base = bm * 128;
  const int colB_base = bn * 128;
  const int sub_r = lane >> 2;
  const int kp = (lane & 3) << 3;

  f32x4 acc[4][4] = {};

  for (int k0 = 0; k0 < KTOT; k0 += 32) {
    __syncthreads();
    #pragma unroll
    for (int i = 0; i < 2; ++i) {
      int chunk = i * 4 + wave;
      int row = chunk * 16 + sub_r;
      const unsigned short* ga = A + (size_t)(rowA_base + row) * KTOT + k0 + kp;
      async_ld16(ga, &As[chunk * 512]);
      const unsigned short* gb = Bt + (size_t)(colB_base + row) * KTOT + k0 + kp;
      async_ld16(gb, &Bs[chunk * 512]);
    }
    __syncthreads();

    bf16x8 a[4], b[4];
    #pragma unroll
    for (int m = 0; m < 4; ++m)
      a[m] = *(const bf16x8*)&As[(wr * 64 + m * 16 + (lane & 15)) * 32 + (lane >> 4) * 8];
    #pragma unroll
    for (int n = 0; n < 4; ++n)
      b[n] = *(const bf16x8*)&Bs[(wc * 64 + n * 16 + (lane & 15)) * 32 + (lane >> 4) * 8];
    #pragma unroll
    for (int m = 0; m < 4; ++m) {
      #pragma unroll
      for (int n = 0; n < 4; ++n)
        acc[m][n] = __builtin_amdgcn_mfma_f32_16x16x32_bf16(a[m], b[n], acc[m][n], 0, 0, 0);
    }
  }

  const int ccol0 = colB_base + wc * 64 + (lane & 15);
  const int crow0 = rowA_base + wr * 64 + ((lane >> 4) << 2);
  #pragma unroll
  for (int m = 0; m < 4; ++m) {
    #pragma unroll
    for (int j = 0; j < 4; ++j) {
      int r = crow0 + m * 16 + j;
      if (r < NNODES) {
        float* cp = C + (size_t)r * FOUTF + ccol0;
        #pragma unroll
        for (int n = 0; n < 4; ++n) cp[n * 16] = acc[m][n][j];
      }
    }
  }
}

// ---------------- launch ----------------

extern "C" void kernel_launch(void* const* d_in, const int* in_sizes, int n_in,
                              void* d_out, int out_size, void* d_ws, size_t ws_size,
                              hipStream_t stream) {
  (void)in_sizes; (void)n_in; (void)out_size; (void)ws_size;
  const float* x  = (const float*)d_in[0];
  const int*   ei = (const int*)d_in[1];
  const float* w  = (const float*)d_in[2];
  float* out = (float*)d_out;

  char* ws = (char*)d_ws;
  size_t off = 0;
  auto carve = [&](size_t bytes) -> void* {
    void* p = ws + off;
    off = (off + bytes + 255) & ~(size_t)255;
    return p;
  };
  unsigned short* z  = (unsigned short*)carve((size_t)MPAD * KTOT * 2);  // 205 MB
  unsigned short* Bt = (unsigned short*)carve((size_t)FOUTF * KTOT * 2);
  int* row_ptr       = (int*)carve((size_t)(NNODES + 1) * 4);
  int* adj           = (int*)carve((size_t)2 * NEDGES * 4);              // 25.6 MB
  int* bcount        = (int*)carve((size_t)(NB + 1) * 4);
  int* bbase         = (int*)carve((size_t)(NB + 1) * 4);
  int* bcursor       = (int*)carve((size_t)(NB + 1) * 4);
  unsigned char* gA  = (unsigned char*)carve((size_t)NNODES * 256);      // 25.6 MB
  unsigned char* gB  = (unsigned char*)carve((size_t)NNODES * 256);      // 25.6 MB
  float* scA         = (float*)carve((size_t)NNODES * 4);
  float* scB         = (float*)carve((size_t)NNODES * 4);
  // binned (51.2 MB) aliases head of z (rows 0..25000): fully consumed by
  // bucket_csr before convert_x/spmm rewrite the region (stream-ordered).
  unsigned long long* binned = (unsigned long long*)z;

  hipMemsetAsync(bcount, 0, (size_t)(NB + 1) * 4, stream);

  bucket_count_kernel<<<1024, 256, 0, stream>>>(ei, bcount);
  bucket_scan_kernel<<<1, 1024, 0, stream>>>(bcount, bbase, bcursor);
  bin_fill_kernel<<<FILLB, 256, 0, stream>>>(ei, bcursor, binned);
  bucket_csr_kernel<<<NB, 256, 0, stream>>>(binned, bbase, row_ptr, adj);

  convert_x_kernel<<<25000, 256, 0, stream>>>(x, z, gA, scA);  // gA,scA = q(x)
  zero_pad_kernel<<<MPAD - NNODES, 256, 0, stream>>>(z);
  convert_w_kernel<<<1024, 256, 0, stream>>>(w, Bt);

  // hop1: q(x)->q(z1); hop2: q(z1)->q(z2); hop3: q(z2)-> (bf16 only)
  spmm_q8_kernel<<<25000, 256, 0, stream>>>(gA, scA, gB, scB, z + 1 * FINF,
                                            row_ptr, adj);
  spmm_q8_kernel<<<25000, 256, 0, stream>>>(gB, scB, gA, scA, z + 2 * FINF,
                                            row_ptr, adj);
  spmm_q8_kernel<<<25000, 256, 0, stream>>>(gA, scA, (unsigned char*)nullptr,
                                            (float*)nullptr, z + 3 * FINF,
                                            row_ptr, adj);

  gemm_kernel<<<MTILES * 2, 256, 0, stream>>>(z, Bt, out);
}